// Round 9
// baseline (778.609 us; speedup 1.0000x reference)
//
#include <hip/hip_runtime.h>
#include <hip/hip_bf16.h>

typedef __hip_bfloat16 bf16;
typedef __bf16 bf8 __attribute__((ext_vector_type(8)));
typedef float  f4  __attribute__((ext_vector_type(4)));

#define N_ATOMS 25000
#define NE      800000
#define NEA     300000
#define NT      1600000
#define APB     64
#define NBUK    ((N_ATOMS + APB - 1) / APB)   // 391

#define DIN0  376   // 16 xi + 64 si + 256 mi + 40 ami
#define DIN1  616   // 256 xi + 64 si + 256 mi + 40 ami
#define DINP0 384   // padded (mult of 32)
#define DINP1 640

#define EBLK ((NE + 4095) / 4096)   // 196

__device__ __forceinline__ float tssr2f(float x) {
    float ax = fabsf(x);
    return (ax <= 1.f) ? x : copysignf(2.f * __builtin_sqrtf(ax) - 1.f, x);
}

// ------------------------------------------------------------------
// Bucket-granularity count: per-block LDS histogram, one flush per block.
// ------------------------------------------------------------------
__global__ __launch_bounds__(256) void k_bcount(const int* __restrict__ esrc,
                                                const int* __restrict__ cat,
                                                int* __restrict__ ebcnt,
                                                int* __restrict__ tbcnt) {
    __shared__ int h[NBUK];
    int t = threadIdx.x;
    for (int b = t; b < NBUK; b += 256) h[b] = 0;
    __syncthreads();
    bool isE = blockIdx.x < EBLK;
    const int* key = isE ? esrc : cat;
    int n = isE ? NE : NT;
    int base = (isE ? blockIdx.x : (blockIdx.x - EBLK)) * 4096;
#pragma unroll
    for (int k = 0; k < 16; k++) {
        int idx = base + k * 256 + t;
        if (idx < n) atomicAdd(&h[key[idx] >> 6], 1);
    }
    __syncthreads();
    int* g = isE ? ebcnt : tbcnt;
    for (int b = t; b < NBUK; b += 256)
        if (h[b]) atomicAdd(&g[b], h[b]);
}

// ------------------------------------------------------------------
// Scan 391 bucket counts -> bucket offsets (+reservation cursors).
// ------------------------------------------------------------------
__global__ __launch_bounds__(512) void k_scanB(const int* cnt0, int* off0, int* cur0,
                                               int* aoff0,
                                               const int* cnt1, int* off1, int* cur1,
                                               int* aoff1) {
    const int* cnt = blockIdx.x ? cnt1 : cnt0;
    int* off  = blockIdx.x ? off1 : off0;
    int* cur  = blockIdx.x ? cur1 : cur0;
    int* aoff = blockIdx.x ? aoff1 : aoff0;
    int nelem = blockIdx.x ? NT : NE;
    __shared__ int sh[512];
    int t = threadIdx.x;
    int v = (t < NBUK) ? cnt[t] : 0;
    sh[t] = v;
    __syncthreads();
    for (int d = 1; d < 512; d <<= 1) {
        int a = (t >= d) ? sh[t - d] : 0;
        __syncthreads();
        sh[t] += a;
        __syncthreads();
    }
    int excl = sh[t] - v;
    if (t <= NBUK) { off[t] = excl; if (t < NBUK) cur[t] = excl; }
    if (t == 0) aoff[N_ATOMS] = nelem;
}

// ------------------------------------------------------------------
// Phase A: bin payloads into coarse buckets (bucket = key >> 6)
// ------------------------------------------------------------------
template <bool EDGE>
__global__ __launch_bounds__(512) void k_binA(const float* __restrict__ fA,
                                              const float* __restrict__ fB,
                                              const int* __restrict__ iB,
                                              const int* __restrict__ iC,
                                              const int* __restrict__ key,
                                              int* __restrict__ gcur,
                                              float4* __restrict__ buk, int n) {
    __shared__ int cnt[NBUK];
    __shared__ int rbase[NBUK];
    int t = threadIdx.x;
    for (int b = t; b < NBUK; b += 512) cnt[b] = 0;
    __syncthreads();
    int base = blockIdx.x * 4096;
    float4 pay[8];
    int bk[8], off[8];
#pragma unroll
    for (int k = 0; k < 8; k++) {
        int idx = base + k * 512 + t;
        bk[k] = -1;
        if (idx < n) {
            float4 p;
            p.x = fA[idx];
            p.y = EDGE ? fB[idx] : __int_as_float(iB[idx]);
            p.z = __int_as_float(iC[idx]);
            int ky = key[idx];
            p.w = __int_as_float(ky);
            pay[k] = p;
            bk[k] = ky >> 6;
            off[k] = atomicAdd(&cnt[bk[k]], 1);
        }
    }
    __syncthreads();
    for (int b = t; b < NBUK; b += 512)
        if (cnt[b]) rbase[b] = atomicAdd(&gcur[b], cnt[b]);
    __syncthreads();
#pragma unroll
    for (int k = 0; k < 8; k++)
        if (bk[k] >= 0) buk[rbase[bk[k]] + off[k]] = pay[k];
}

// ------------------------------------------------------------------
// Phase B: one workgroup per bucket; derives per-atom CSR offsets in LDS
// ------------------------------------------------------------------
__global__ __launch_bounds__(256) void k_binB(const int* __restrict__ bkoff,
                                              const float4* __restrict__ buk,
                                              float4* __restrict__ fin,
                                              int* __restrict__ aoff) {
    int b = blockIdx.x;
    int lo = b * APB;
    int hi = min(lo + APB, N_ATOMS);
    __shared__ int cnt[APB];
    __shared__ int cur[APB];
    int t = threadIdx.x;
    if (t < APB) cnt[t] = 0;
    __syncthreads();
    int pbeg = bkoff[b], pend = bkoff[b + 1];
    for (int p = pbeg + t; p < pend; p += 256) {
        int a = __float_as_int(((const float*)(buk + p))[3]);
        atomicAdd(&cnt[a - lo], 1);
    }
    __syncthreads();
    if (t == 0) {
        int run = pbeg;
        for (int k = 0; k < hi - lo; k++) {
            cur[k] = run;
            aoff[lo + k] = run;
            run += cnt[k];
        }
    }
    __syncthreads();
    for (int p = pbeg + t; p < pend; p += 256) {
        float4 pay = buk[p];
        int a = __float_as_int(pay.w);
        int slot = atomicAdd(&cur[a - lo], 1);
        fin[slot] = pay;
    }
}

// ------------------------------------------------------------------
// W -> bf16 fragment layout (generalized): frag f = (chunk*ntiles + tile)*64 + lane
// ------------------------------------------------------------------
__global__ void k_wprep(const float* __restrict__ W, bf8* __restrict__ Wf,
                        int K, int N, int ntiles, int nfrag) {
    int f = blockIdx.x * blockDim.x + threadIdx.x;
    if (f >= nfrag) return;
    int lane = f & 63;
    int ft = f >> 6;
    int tile = ft % ntiles;
    int chunk = ft / ntiles;
    int n = tile * 16 + (lane & 15);
    int kb = chunk * 32 + (lane >> 4) * 8;
    bf8 v;
#pragma unroll
    for (int j = 0; j < 8; j++) {
        int k = kb + j;
        v[j] = (__bf16)((k < K) ? W[k * N + n] : 0.f);
    }
    Wf[f] = v;
}

// ------------------------------------------------------------------
// layer 0: ei0[:,0:16) = table[sp]; s = table[sp] @ W_si0 (16x96); pad zeros
// ------------------------------------------------------------------
__global__ void k_s0(const int* __restrict__ sp, const float* __restrict__ table,
                     const float* __restrict__ W, float* __restrict__ ei0,
                     float* __restrict__ sd) {
    int idx = blockIdx.x * blockDim.x + threadIdx.x;
    if (idx >= N_ATOMS * 120) return;
    int i = idx / 120;
    int c = idx - i * 120;
    if (c >= 112) {
        ei0[(size_t)i * DINP0 + 376 + (c - 112)] = 0.f;
        return;
    }
    int s = sp[i];
    if (c < 16) {
        ei0[(size_t)i * DINP0 + c] = table[s * 16 + c];
    } else {
        int cc = c - 16;
        float acc = 0.f;
#pragma unroll
        for (int k = 0; k < 16; k++)
            acc += table[s * 16 + k] * W[k * 96 + cc];
        if (cc < 64) ei0[(size_t)i * DINP0 + 16 + cc] = acc;
        else         sd[i * 32 + cc - 64]             = acc;
    }
}

// ------------------------------------------------------------------
// layer 1 s: MFMA GEMM 25000x96 = xi(25000x256) @ W_si1(256x96)
// ------------------------------------------------------------------
__global__ __launch_bounds__(256) void k_s1(const float* __restrict__ ei1,
                                            const bf8* __restrict__ Wf,
                                            float* __restrict__ ei1o,
                                            float* __restrict__ sd) {
    __shared__ __align__(16) __bf16 Asg[4][64][8];
    int t = threadIdx.x;
    int w = t >> 6, lane = t & 63;
    int a0 = blockIdx.x * 64;

    int satom = a0 + (t >> 2);
    int k8 = (t & 3) * 8;
    const float* arow = &ei1[(size_t)satom * DINP1 + k8];
    bool aok = satom < N_ATOMS;
    int dw = (t >> 2) >> 4;
    int dl = ((t >> 2) & 15) | ((t & 3) << 4);
    __bf16* adst = &Asg[dw][dl][0];

    f4 acc[6];
#pragma unroll
    for (int j = 0; j < 6; j++) {
        f4 z = {0.f, 0.f, 0.f, 0.f};
        acc[j] = z;
    }

    for (int ch = 0; ch < 8; ch++) {
        float4 v0 = make_float4(0.f, 0.f, 0.f, 0.f);
        float4 v1 = make_float4(0.f, 0.f, 0.f, 0.f);
        if (aok) {
            v0 = *(const float4*)(arow + ch * 32);
            v1 = *(const float4*)(arow + ch * 32 + 4);
        }
        __syncthreads();
        adst[0] = (__bf16)v0.x; adst[1] = (__bf16)v0.y;
        adst[2] = (__bf16)v0.z; adst[3] = (__bf16)v0.w;
        adst[4] = (__bf16)v1.x; adst[5] = (__bf16)v1.y;
        adst[6] = (__bf16)v1.z; adst[7] = (__bf16)v1.w;
        __syncthreads();
        bf8 afr = *(const bf8*)&Asg[w][lane][0];
        const bf8* wp = &Wf[(ch * 6) * 64 + lane];
#pragma unroll
        for (int tn = 0; tn < 6; tn++) {
            bf8 b = wp[tn * 64];
            acc[tn] = __builtin_amdgcn_mfma_f32_16x16x32_bf16(afr, b, acc[tn], 0, 0, 0);
        }
    }

    int nlo = lane & 15, q = lane >> 4;
#pragma unroll
    for (int r = 0; r < 4; r++) {
        int atom = a0 + w * 16 + q * 4 + r;
        if (atom < N_ATOMS) {
#pragma unroll
            for (int tn = 0; tn < 6; tn++) {
                int col = tn * 16 + nlo;
                float v = acc[tn][r];
                if (col < 64) ei1o[(size_t)atom * DINP1 + 256 + col] = v;
                else          sd[atom * 32 + col - 64] = v;
            }
        }
    }
    for (int z = t; z < 64 * 24; z += 256) {
        int za = a0 + z / 24;
        if (za < N_ATOMS) ei1o[(size_t)za * DINP1 + 616 + z % 24] = 0.f;
    }
}

// ------------------------------------------------------------------
// da = (bessel(dist_angle)*switch_angle) @ W_da   -> EA x 8 fp32
// ------------------------------------------------------------------
__global__ void k_da(const float* __restrict__ dist, const float* __restrict__ sw,
                     const float* __restrict__ W, float* __restrict__ da) {
    int e = blockIdx.x * blockDim.x + threadIdx.x;
    if (e >= NEA) return;
    float d = dist[e];
    float s = sw[e];
    float rb[8];
#pragma unroll
    for (int n = 0; n < 8; n++)
        rb[n] = 0.7559289460f * __sinf((n + 1) * 0.8975979010f * d) / d * s;
    float w[8];
#pragma unroll
    for (int c = 0; c < 8; c++) {
        float acc = 0.f;
#pragma unroll
        for (int n = 0; n < 8; n++) acc += rb[n] * W[n * 8 + c];
        w[c] = acc;
    }
#pragma unroll
    for (int c = 0; c < 8; c++) da[e * 8 + c] = w[c];
}

// ------------------------------------------------------------------
// mi: one WAVE per atom, no LDS, no barriers.
// lane l: n = l>>3, cols cb..cb+3. Payload loads are wave-uniform
// (HW broadcast); sd gathers are 8-lane-shared float4.
// ------------------------------------------------------------------
__global__ __launch_bounds__(256) void k_mi(const int* __restrict__ eoff,
                                            const float4* __restrict__ epay,
                                            const float* __restrict__ sd,
                                            float* __restrict__ mo, int stride) {
    int t = threadIdx.x;
    int w = t >> 6, l = t & 63;
    int i = blockIdx.x * 4 + w;
    if (i >= N_ATOMS) return;
    int beg = eoff[i], end = eoff[i + 1];
    int n = l >> 3, cb = (l & 7) * 4;
    float kn = (n + 1) * 0.6283185307f;
    float4 acc = make_float4(0.f, 0.f, 0.f, 0.f);
    for (int base = beg; base < end; base += 8) {
        int m = end - base;
#pragma unroll
        for (int j = 0; j < 8; j++) {
            if (j < m) {
                float4 ep = epay[base + j];
                float d = ep.x, s = ep.y;
                int di = __float_as_int(ep.z);
                float rb = 0.6324555320f * __sinf(kn * d) / d * s;
                float4 v = *(const float4*)&sd[di * 32 + cb];
                acc.x += rb * v.x; acc.y += rb * v.y;
                acc.z += rb * v.z; acc.w += rb * v.w;
            }
        }
    }
    *(float4*)&mo[(size_t)i * stride + n * 32 + cb] = acc;
}

// ------------------------------------------------------------------
// ami: one WAVE per atom, no LDS, no barriers. lanes 0..39: n=l>>3, c=l&7.
// ------------------------------------------------------------------
__global__ __launch_bounds__(256) void k_ami(const int* __restrict__ toff,
                                             const float4* __restrict__ tpay,
                                             const float* __restrict__ da,
                                             float* __restrict__ ao, int stride) {
    int t = threadIdx.x;
    int w = t >> 6, l = t & 63;
    int i = blockIdx.x * 4 + w;
    if (i >= N_ATOMS) return;
    if (l < 40) {
        int beg = toff[i], end = toff[i + 1];
        int n = l >> 3, c = l & 7;
        float fn = (float)n;
        float acc = 0.f;
        for (int base = beg; base < end; base += 8) {
            int m = end - base;
#pragma unroll
            for (int j = 0; j < 8; j++) {
                if (j < m) {
                    float4 tp = tpay[base + j];
                    int ea = __float_as_int(tp.y), eb = __float_as_int(tp.z);
                    float dij = da[ea * 8 + c] * da[eb * 8 + c];
                    acc += __cosf(fn * tp.x) * dij;
                }
            }
        }
        ao[(size_t)i * stride + l] = acc;
    }
}

// ------------------------------------------------------------------
// MFMA GEMM: dxi = tssr2(ei @ W + b)
// ------------------------------------------------------------------
template <int LAYER>
__global__ __launch_bounds__(256) void k_gemm(const float* __restrict__ ei,
                                              const bf8* __restrict__ Wf,
                                              const float* __restrict__ bias,
                                              const float* __restrict__ skip,
                                              float* __restrict__ out) {
    constexpr int DINP = (LAYER == 0) ? DINP0 : DINP1;
    constexpr int NCH = DINP / 32;
    __shared__ __align__(16) __bf16 Asg[2][64][8];
    int t = threadIdx.x;
    int w = t >> 6, lane = t & 63;
    int a0 = blockIdx.x * 32;

    int f  = t * 4;
    int tA = f >> 9;
    int al = (f >> 3) & 63;
    int j0 = f & 7;
    int sm = al & 15, sq = al >> 4;
    int ga = a0 + tA * 16 + sm;
    const float* arow = &ei[(size_t)ga * DINP + sq * 8 + j0];
    __bf16* adst = &Asg[0][0][0] + f;
    bool aok = (ga < N_ATOMS);

    f4 acc[2][4];
#pragma unroll
    for (int i = 0; i < 2; i++)
#pragma unroll
        for (int j = 0; j < 4; j++) {
            f4 z = {0.f, 0.f, 0.f, 0.f};
            acc[i][j] = z;
        }

    for (int ch = 0; ch < NCH; ch++) {
        float4 v = make_float4(0.f, 0.f, 0.f, 0.f);
        if (aok) v = *(const float4*)(arow + ch * 32);
        __syncthreads();
        adst[0] = (__bf16)v.x; adst[1] = (__bf16)v.y;
        adst[2] = (__bf16)v.z; adst[3] = (__bf16)v.w;
        __syncthreads();
        bf8 afr0 = *(const bf8*)&Asg[0][lane][0];
        bf8 afr1 = *(const bf8*)&Asg[1][lane][0];
        const bf8* wp = &Wf[(ch * 16 + w * 4) * 64 + lane];
#pragma unroll
        for (int tn = 0; tn < 4; tn++) {
            bf8 b = wp[tn * 64];
            acc[0][tn] = __builtin_amdgcn_mfma_f32_16x16x32_bf16(afr0, b, acc[0][tn], 0, 0, 0);
            acc[1][tn] = __builtin_amdgcn_mfma_f32_16x16x32_bf16(afr1, b, acc[1][tn], 0, 0, 0);
        }
    }

    int nlo = lane & 15, q = lane >> 4;
#pragma unroll
    for (int tA2 = 0; tA2 < 2; tA2++) {
#pragma unroll
        for (int r = 0; r < 4; r++) {
            int atom = a0 + tA2 * 16 + q * 4 + r;
            if (atom < N_ATOMS) {
#pragma unroll
                for (int tn = 0; tn < 4; tn++) {
                    int col = w * 64 + tn * 16 + nlo;
                    float vv = tssr2f(acc[tA2][tn][r] + bias[col]);
                    if (LAYER == 0) {
                        out[(size_t)atom * DINP1 + col] = vv;
                    } else {
                        out[(size_t)atom * 256 + col] = vv + skip[(size_t)atom * DINP1 + col];
                    }
                }
            }
        }
    }
}

// ------------------------------------------------------------------
extern "C" void kernel_launch(void* const* d_in, const int* in_sizes, int n_in,
                              void* d_out, int out_size, void* d_ws, size_t ws_size,
                              hipStream_t stream) {
    const int*   species     = (const int*)d_in[0];
    const int*   edge_src    = (const int*)d_in[1];
    const int*   edge_dst    = (const int*)d_in[2];
    const float* distances   = (const float*)d_in[3];
    const float* sw          = (const float*)d_in[4];
    const float* angles      = (const float*)d_in[5];
    const int*   angle_src   = (const int*)d_in[6];
    const int*   angle_dst   = (const int*)d_in[7];
    const int*   central     = (const int*)d_in[8];
    const float* dist_a      = (const float*)d_in[9];
    const float* sw_a        = (const float*)d_in[10];
    const float* table       = (const float*)d_in[11];
    const float* W_si0       = (const float*)d_in[12];
    const float* W_si1       = (const float*)d_in[13];
    const float* W_da0       = (const float*)d_in[14];
    const float* W_da1       = (const float*)d_in[15];
    const float* W_mix0      = (const float*)d_in[16];
    const float* b_mix0      = (const float*)d_in[17];
    const float* W_mix1      = (const float*)d_in[18];
    const float* b_mix1      = (const float*)d_in[19];
    float* out = (float*)d_out;

    char* p = (char*)d_ws;
    auto alloc = [&](size_t bytes) {
        char* r = p;
        p += (bytes + 255) & ~(size_t)255;
        return (void*)r;
    };
    float*  ei0  = (float*)alloc((size_t)N_ATOMS * DINP0 * 4);
    float*  ei1  = (float*)alloc((size_t)N_ATOMS * DINP1 * 4);
    float*  sd   = (float*)alloc((size_t)N_ATOMS * 32 * 4);
    float*  da   = (float*)alloc((size_t)NEA * 8 * 4);
    float4* epay = (float4*)alloc((size_t)NE * 16);
    float4* tpay = (float4*)alloc((size_t)NT * 16);
    bf8*    Wf0  = (bf8*)alloc((size_t)(DINP0 / 32) * 16 * 64 * 16);
    bf8*    Wf1  = (bf8*)alloc((size_t)(DINP1 / 32) * 16 * 64 * 16);
    bf8*    WfS1 = (bf8*)alloc((size_t)8 * 6 * 64 * 16);
    int* eoff   = (int*)alloc((size_t)(N_ATOMS + 1) * 4);
    int* toff   = (int*)alloc((size_t)(N_ATOMS + 1) * 4);
    int* ebcnt  = (int*)alloc((size_t)NBUK * 4);
    int* tbcnt  = (int*)alloc((size_t)NBUK * 4);
    int* ebkoff = (int*)alloc((size_t)(NBUK + 1) * 4);
    int* tbkoff = (int*)alloc((size_t)(NBUK + 1) * 4);
    int* gce    = (int*)alloc((size_t)NBUK * 4);
    int* gct    = (int*)alloc((size_t)NBUK * 4);
    (void)ws_size;

    // bucket staging arrays alias ei1 (written only later by k_gemm<0>)
    float4* tbuk = (float4*)ei1;
    float4* ebuk = (float4*)((char*)ei1 + (size_t)NT * 16);

    hipMemsetAsync(ebcnt, 0, (size_t)NBUK * 4, stream);
    hipMemsetAsync(tbcnt, 0, (size_t)NBUK * 4, stream);

    int nfrag0 = (DINP0 / 32) * 16 * 64;
    int nfrag1 = (DINP1 / 32) * 16 * 64;
    int nfragS = 8 * 6 * 64;
    k_wprep<<<(nfrag0 + 255) / 256, 256, 0, stream>>>(W_mix0, Wf0, DIN0, 256, 16, nfrag0);
    k_wprep<<<(nfrag1 + 255) / 256, 256, 0, stream>>>(W_mix1, Wf1, DIN1, 256, 16, nfrag1);
    k_wprep<<<(nfragS + 255) / 256, 256, 0, stream>>>(W_si1, WfS1, 256, 96, 6, nfragS);

    k_bcount<<<EBLK + (NT + 4095) / 4096, 256, 0, stream>>>(edge_src, central, ebcnt, tbcnt);
    k_scanB<<<2, 512, 0, stream>>>(ebcnt, ebkoff, gce, eoff, tbcnt, tbkoff, gct, toff);

    k_binA<true><<<(NE + 4095) / 4096, 512, 0, stream>>>(
        distances, sw, nullptr, edge_dst, edge_src, gce, ebuk, NE);
    k_binA<false><<<(NT + 4095) / 4096, 512, 0, stream>>>(
        angles, nullptr, angle_src, angle_dst, central, gct, tbuk, NT);
    k_binB<<<NBUK, 256, 0, stream>>>(ebkoff, ebuk, epay, eoff);
    k_binB<<<NBUK, 256, 0, stream>>>(tbkoff, tbuk, tpay, toff);

    int gemm_grid = (N_ATOMS + 31) / 32;
    int seg_grid = (N_ATOMS + 3) / 4;

    // ---- layer 0 ----
    k_s0<<<(N_ATOMS * 120 + 255) / 256, 256, 0, stream>>>(species, table, W_si0, ei0, sd);
    k_da<<<(NEA + 255) / 256, 256, 0, stream>>>(dist_a, sw_a, W_da0, da);
    k_mi<<<seg_grid, 256, 0, stream>>>(eoff, epay, sd, ei0 + 80, DINP0);
    k_ami<<<seg_grid, 256, 0, stream>>>(toff, tpay, da, ei0 + 336, DINP0);
    k_gemm<0><<<gemm_grid, 256, 0, stream>>>(ei0, Wf0, b_mix0, nullptr, ei1);

    // ---- layer 1 ----
    k_s1<<<(N_ATOMS + 63) / 64, 256, 0, stream>>>(ei1, WfS1, ei1, sd);
    k_da<<<(NEA + 255) / 256, 256, 0, stream>>>(dist_a, sw_a, W_da1, da);
    k_mi<<<seg_grid, 256, 0, stream>>>(eoff, epay, sd, ei1 + 320, DINP1);
    k_ami<<<seg_grid, 256, 0, stream>>>(toff, tpay, da, ei1 + 576, DINP1);
    k_gemm<1><<<gemm_grid, 256, 0, stream>>>(ei1, Wf1, b_mix1, ei1, out);
}

// Round 10
// 573.128 us; speedup vs baseline: 1.3585x; 1.3585x over previous
//
#include <hip/hip_runtime.h>
#include <hip/hip_bf16.h>

typedef __hip_bfloat16 bf16;
typedef __bf16 bf8 __attribute__((ext_vector_type(8)));
typedef float  f4  __attribute__((ext_vector_type(4)));

#define N_ATOMS 25000
#define NE      800000
#define NEA     300000
#define NT      1600000
#define APB     64
#define NBUK    ((N_ATOMS + APB - 1) / APB)   // 391

#define DIN0  376
#define DIN1  616
#define DINP0 384
#define DINP1 640

#define EBLK ((NE + 4095) / 4096)   // 196

__device__ __forceinline__ float tssr2f(float x) {
    float ax = fabsf(x);
    return (ax <= 1.f) ? x : copysignf(2.f * __builtin_sqrtf(ax) - 1.f, x);
}

__device__ __forceinline__ unsigned short f2bf_rn(float v) {
    unsigned int b = __float_as_uint(v);
    b += 0x7FFF + ((b >> 16) & 1);
    return (unsigned short)(b >> 16);
}
__device__ __forceinline__ float bf2f(unsigned short u) {
    return __uint_as_float(((unsigned int)u) << 16);
}

// ------------------------------------------------------------------
// Bucket-granularity count
// ------------------------------------------------------------------
__global__ __launch_bounds__(256) void k_bcount(const int* __restrict__ esrc,
                                                const int* __restrict__ cat,
                                                int* __restrict__ ebcnt,
                                                int* __restrict__ tbcnt) {
    __shared__ int h[NBUK];
    int t = threadIdx.x;
    for (int b = t; b < NBUK; b += 256) h[b] = 0;
    __syncthreads();
    bool isE = blockIdx.x < EBLK;
    const int* key = isE ? esrc : cat;
    int n = isE ? NE : NT;
    int base = (isE ? blockIdx.x : (blockIdx.x - EBLK)) * 4096;
#pragma unroll
    for (int k = 0; k < 16; k++) {
        int idx = base + k * 256 + t;
        if (idx < n) atomicAdd(&h[key[idx] >> 6], 1);
    }
    __syncthreads();
    int* g = isE ? ebcnt : tbcnt;
    for (int b = t; b < NBUK; b += 256)
        if (h[b]) atomicAdd(&g[b], h[b]);
}

// ------------------------------------------------------------------
// Scan 391 bucket counts
// ------------------------------------------------------------------
__global__ __launch_bounds__(512) void k_scanB(const int* cnt0, int* off0, int* cur0,
                                               int* aoff0,
                                               const int* cnt1, int* off1, int* cur1,
                                               int* aoff1) {
    const int* cnt = blockIdx.x ? cnt1 : cnt0;
    int* off  = blockIdx.x ? off1 : off0;
    int* cur  = blockIdx.x ? cur1 : cur0;
    int* aoff = blockIdx.x ? aoff1 : aoff0;
    int nelem = blockIdx.x ? NT : NE;
    __shared__ int sh[512];
    int t = threadIdx.x;
    int v = (t < NBUK) ? cnt[t] : 0;
    sh[t] = v;
    __syncthreads();
    for (int d = 1; d < 512; d <<= 1) {
        int a = (t >= d) ? sh[t - d] : 0;
        __syncthreads();
        sh[t] += a;
        __syncthreads();
    }
    int excl = sh[t] - v;
    if (t <= NBUK) { off[t] = excl; if (t < NBUK) cur[t] = excl; }
    if (t == 0) aoff[N_ATOMS] = nelem;
}

// ------------------------------------------------------------------
// Phase A: bin payloads into coarse buckets
// ------------------------------------------------------------------
template <bool EDGE>
__global__ __launch_bounds__(512) void k_binA(const float* __restrict__ fA,
                                              const float* __restrict__ fB,
                                              const int* __restrict__ iB,
                                              const int* __restrict__ iC,
                                              const int* __restrict__ key,
                                              int* __restrict__ gcur,
                                              float4* __restrict__ buk, int n) {
    __shared__ int cnt[NBUK];
    __shared__ int rbase[NBUK];
    int t = threadIdx.x;
    for (int b = t; b < NBUK; b += 512) cnt[b] = 0;
    __syncthreads();
    int base = blockIdx.x * 4096;
    float4 pay[8];
    int bk[8], off[8];
#pragma unroll
    for (int k = 0; k < 8; k++) {
        int idx = base + k * 512 + t;
        bk[k] = -1;
        if (idx < n) {
            float4 p;
            p.x = fA[idx];
            p.y = EDGE ? fB[idx] : __int_as_float(iB[idx]);
            p.z = __int_as_float(iC[idx]);
            int ky = key[idx];
            p.w = __int_as_float(ky);
            pay[k] = p;
            bk[k] = ky >> 6;
            off[k] = atomicAdd(&cnt[bk[k]], 1);
        }
    }
    __syncthreads();
    for (int b = t; b < NBUK; b += 512)
        if (cnt[b]) rbase[b] = atomicAdd(&gcur[b], cnt[b]);
    __syncthreads();
#pragma unroll
    for (int k = 0; k < 8; k++)
        if (bk[k] >= 0) buk[rbase[bk[k]] + off[k]] = pay[k];
}

// ------------------------------------------------------------------
// Phase B: one workgroup per bucket
// ------------------------------------------------------------------
__global__ __launch_bounds__(256) void k_binB(const int* __restrict__ bkoff,
                                              const float4* __restrict__ buk,
                                              float4* __restrict__ fin,
                                              int* __restrict__ aoff) {
    int b = blockIdx.x;
    int lo = b * APB;
    int hi = min(lo + APB, N_ATOMS);
    __shared__ int cnt[APB];
    __shared__ int cur[APB];
    int t = threadIdx.x;
    if (t < APB) cnt[t] = 0;
    __syncthreads();
    int pbeg = bkoff[b], pend = bkoff[b + 1];
    for (int p = pbeg + t; p < pend; p += 256) {
        int a = __float_as_int(((const float*)(buk + p))[3]);
        atomicAdd(&cnt[a - lo], 1);
    }
    __syncthreads();
    if (t == 0) {
        int run = pbeg;
        for (int k = 0; k < hi - lo; k++) {
            cur[k] = run;
            aoff[lo + k] = run;
            run += cnt[k];
        }
    }
    __syncthreads();
    for (int p = pbeg + t; p < pend; p += 256) {
        float4 pay = buk[p];
        int a = __float_as_int(pay.w);
        int slot = atomicAdd(&cur[a - lo], 1);
        fin[slot] = pay;
    }
}

// ------------------------------------------------------------------
// W -> bf16 fragment layout (generalized)
// ------------------------------------------------------------------
__global__ void k_wprep(const float* __restrict__ W, bf8* __restrict__ Wf,
                        int K, int N, int ntiles, int nfrag) {
    int f = blockIdx.x * blockDim.x + threadIdx.x;
    if (f >= nfrag) return;
    int lane = f & 63;
    int ft = f >> 6;
    int tile = ft % ntiles;
    int chunk = ft / ntiles;
    int n = tile * 16 + (lane & 15);
    int kb = chunk * 32 + (lane >> 4) * 8;
    bf8 v;
#pragma unroll
    for (int j = 0; j < 8; j++) {
        int k = kb + j;
        v[j] = (__bf16)((k < K) ? W[k * N + n] : 0.f);
    }
    Wf[f] = v;
}

// ------------------------------------------------------------------
// layer 0
// ------------------------------------------------------------------
__global__ void k_s0(const int* __restrict__ sp, const float* __restrict__ table,
                     const float* __restrict__ W, float* __restrict__ ei0,
                     float* __restrict__ sd) {
    int idx = blockIdx.x * blockDim.x + threadIdx.x;
    if (idx >= N_ATOMS * 120) return;
    int i = idx / 120;
    int c = idx - i * 120;
    if (c >= 112) {
        ei0[(size_t)i * DINP0 + 376 + (c - 112)] = 0.f;
        return;
    }
    int s = sp[i];
    if (c < 16) {
        ei0[(size_t)i * DINP0 + c] = table[s * 16 + c];
    } else {
        int cc = c - 16;
        float acc = 0.f;
#pragma unroll
        for (int k = 0; k < 16; k++)
            acc += table[s * 16 + k] * W[k * 96 + cc];
        if (cc < 64) ei0[(size_t)i * DINP0 + 16 + cc] = acc;
        else         sd[i * 32 + cc - 64]             = acc;
    }
}

// ------------------------------------------------------------------
// layer 1 s: MFMA GEMM 25000x96
// ------------------------------------------------------------------
__global__ __launch_bounds__(256) void k_s1(const float* __restrict__ ei1,
                                            const bf8* __restrict__ Wf,
                                            float* __restrict__ ei1o,
                                            float* __restrict__ sd) {
    __shared__ __align__(16) __bf16 Asg[4][64][8];
    int t = threadIdx.x;
    int w = t >> 6, lane = t & 63;
    int a0 = blockIdx.x * 64;

    int satom = a0 + (t >> 2);
    int k8 = (t & 3) * 8;
    const float* arow = &ei1[(size_t)satom * DINP1 + k8];
    bool aok = satom < N_ATOMS;
    int dw = (t >> 2) >> 4;
    int dl = ((t >> 2) & 15) | ((t & 3) << 4);
    __bf16* adst = &Asg[dw][dl][0];

    f4 acc[6];
#pragma unroll
    for (int j = 0; j < 6; j++) {
        f4 z = {0.f, 0.f, 0.f, 0.f};
        acc[j] = z;
    }

    for (int ch = 0; ch < 8; ch++) {
        float4 v0 = make_float4(0.f, 0.f, 0.f, 0.f);
        float4 v1 = make_float4(0.f, 0.f, 0.f, 0.f);
        if (aok) {
            v0 = *(const float4*)(arow + ch * 32);
            v1 = *(const float4*)(arow + ch * 32 + 4);
        }
        __syncthreads();
        adst[0] = (__bf16)v0.x; adst[1] = (__bf16)v0.y;
        adst[2] = (__bf16)v0.z; adst[3] = (__bf16)v0.w;
        adst[4] = (__bf16)v1.x; adst[5] = (__bf16)v1.y;
        adst[6] = (__bf16)v1.z; adst[7] = (__bf16)v1.w;
        __syncthreads();
        bf8 afr = *(const bf8*)&Asg[w][lane][0];
        const bf8* wp = &Wf[(ch * 6) * 64 + lane];
#pragma unroll
        for (int tn = 0; tn < 6; tn++) {
            bf8 b = wp[tn * 64];
            acc[tn] = __builtin_amdgcn_mfma_f32_16x16x32_bf16(afr, b, acc[tn], 0, 0, 0);
        }
    }

    int nlo = lane & 15, q = lane >> 4;
#pragma unroll
    for (int r = 0; r < 4; r++) {
        int atom = a0 + w * 16 + q * 4 + r;
        if (atom < N_ATOMS) {
#pragma unroll
            for (int tn = 0; tn < 6; tn++) {
                int col = tn * 16 + nlo;
                float v = acc[tn][r];
                if (col < 64) ei1o[(size_t)atom * DINP1 + 256 + col] = v;
                else          sd[atom * 32 + col - 64] = v;
            }
        }
    }
    for (int z = t; z < 64 * 24; z += 256) {
        int za = a0 + z / 24;
        if (za < N_ATOMS) ei1o[(size_t)za * DINP1 + 616 + z % 24] = 0.f;
    }
}

// ------------------------------------------------------------------
// da -> bf16 (EA x 8), halves the k_ami gather footprint (9.6 -> 4.8 MB)
// ------------------------------------------------------------------
__global__ void k_da(const float* __restrict__ dist, const float* __restrict__ sw,
                     const float* __restrict__ W, unsigned short* __restrict__ dah) {
    int e = blockIdx.x * blockDim.x + threadIdx.x;
    if (e >= NEA) return;
    float d = dist[e];
    float s = sw[e];
    float rb[8];
#pragma unroll
    for (int n = 0; n < 8; n++)
        rb[n] = 0.7559289460f * __sinf((n + 1) * 0.8975979010f * d) / d * s;
    unsigned short h[8];
#pragma unroll
    for (int c = 0; c < 8; c++) {
        float acc = 0.f;
#pragma unroll
        for (int n = 0; n < 8; n++) acc += rb[n] * W[n * 8 + c];
        h[c] = f2bf_rn(acc);
    }
    *(uint4*)&dah[e * 8] = *(uint4*)h;
}

// ------------------------------------------------------------------
// mi: one WAVE per atom; branchless full groups of 8, masked tail.
// ------------------------------------------------------------------
__global__ __launch_bounds__(256) void k_mi(const int* __restrict__ eoff,
                                            const float4* __restrict__ epay,
                                            const float* __restrict__ sd,
                                            float* __restrict__ mo, int stride) {
    int t = threadIdx.x;
    int w = t >> 6, l = t & 63;
    int i = blockIdx.x * 4 + w;
    if (i >= N_ATOMS) return;
    int beg = eoff[i], end = eoff[i + 1];
    int n = l >> 3, cb = (l & 7) * 4;
    float kn = (n + 1) * 0.6283185307f;
    float4 acc = make_float4(0.f, 0.f, 0.f, 0.f);
    int base = beg;
    for (; base + 8 <= end; base += 8) {
#pragma unroll
        for (int j = 0; j < 8; j++) {
            float4 ep = epay[base + j];
            float d = ep.x, s = ep.y;
            int di = __float_as_int(ep.z);
            float rb = 0.6324555320f * __sinf(kn * d) / d * s;
            float4 v = *(const float4*)&sd[di * 32 + cb];
            acc.x += rb * v.x; acc.y += rb * v.y;
            acc.z += rb * v.z; acc.w += rb * v.w;
        }
    }
    if (base < end) {
        int m = end - base;
#pragma unroll
        for (int j = 0; j < 8; j++) {
            int p = base + min(j, m - 1);
            float4 ep = epay[p];
            float d = ep.x, s = ep.y;
            int di = __float_as_int(ep.z);
            float mask = (j < m) ? 1.f : 0.f;
            float rb = mask * 0.6324555320f * __sinf(kn * d) / d * s;
            float4 v = *(const float4*)&sd[di * 32 + cb];
            acc.x += rb * v.x; acc.y += rb * v.y;
            acc.z += rb * v.z; acc.w += rb * v.w;
        }
    }
    *(float4*)&mo[(size_t)i * stride + n * 32 + cb] = acc;
}

// ------------------------------------------------------------------
// ami: one WAVE per atom; branchless full groups of 8, masked tail.
// da gathers are 2B bf16 per lane.
// ------------------------------------------------------------------
__global__ __launch_bounds__(256) void k_ami(const int* __restrict__ toff,
                                             const float4* __restrict__ tpay,
                                             const unsigned short* __restrict__ dah,
                                             float* __restrict__ ao, int stride) {
    int t = threadIdx.x;
    int w = t >> 6, l = t & 63;
    int i = blockIdx.x * 4 + w;
    if (i >= N_ATOMS) return;
    if (l < 40) {
        int beg = toff[i], end = toff[i + 1];
        int n = l >> 3, c = l & 7;
        float fn = (float)n;
        float acc = 0.f;
        int base = beg;
        for (; base + 8 <= end; base += 8) {
#pragma unroll
            for (int j = 0; j < 8; j++) {
                float4 tp = tpay[base + j];
                int ea = __float_as_int(tp.y), eb = __float_as_int(tp.z);
                float dij = bf2f(dah[ea * 8 + c]) * bf2f(dah[eb * 8 + c]);
                acc += __cosf(fn * tp.x) * dij;
            }
        }
        if (base < end) {
            int m = end - base;
#pragma unroll
            for (int j = 0; j < 8; j++) {
                int p = base + min(j, m - 1);
                float4 tp = tpay[p];
                int ea = __float_as_int(tp.y), eb = __float_as_int(tp.z);
                float mask = (j < m) ? 1.f : 0.f;
                float dij = bf2f(dah[ea * 8 + c]) * bf2f(dah[eb * 8 + c]);
                acc += mask * __cosf(fn * tp.x) * dij;
            }
        }
        ao[(size_t)i * stride + l] = acc;
    }
}

// ------------------------------------------------------------------
// MFMA GEMM: dxi = tssr2(ei @ W + b)
// ------------------------------------------------------------------
template <int LAYER>
__global__ __launch_bounds__(256) void k_gemm(const float* __restrict__ ei,
                                              const bf8* __restrict__ Wf,
                                              const float* __restrict__ bias,
                                              const float* __restrict__ skip,
                                              float* __restrict__ out) {
    constexpr int DINP = (LAYER == 0) ? DINP0 : DINP1;
    constexpr int NCH = DINP / 32;
    __shared__ __align__(16) __bf16 Asg[2][64][8];
    int t = threadIdx.x;
    int w = t >> 6, lane = t & 63;
    int a0 = blockIdx.x * 32;

    int f  = t * 4;
    int tA = f >> 9;
    int al = (f >> 3) & 63;
    int j0 = f & 7;
    int sm = al & 15, sq = al >> 4;
    int ga = a0 + tA * 16 + sm;
    const float* arow = &ei[(size_t)ga * DINP + sq * 8 + j0];
    __bf16* adst = &Asg[0][0][0] + f;
    bool aok = (ga < N_ATOMS);

    f4 acc[2][4];
#pragma unroll
    for (int i = 0; i < 2; i++)
#pragma unroll
        for (int j = 0; j < 4; j++) {
            f4 z = {0.f, 0.f, 0.f, 0.f};
            acc[i][j] = z;
        }

    for (int ch = 0; ch < NCH; ch++) {
        float4 v = make_float4(0.f, 0.f, 0.f, 0.f);
        if (aok) v = *(const float4*)(arow + ch * 32);
        __syncthreads();
        adst[0] = (__bf16)v.x; adst[1] = (__bf16)v.y;
        adst[2] = (__bf16)v.z; adst[3] = (__bf16)v.w;
        __syncthreads();
        bf8 afr0 = *(const bf8*)&Asg[0][lane][0];
        bf8 afr1 = *(const bf8*)&Asg[1][lane][0];
        const bf8* wp = &Wf[(ch * 16 + w * 4) * 64 + lane];
#pragma unroll
        for (int tn = 0; tn < 4; tn++) {
            bf8 b = wp[tn * 64];
            acc[0][tn] = __builtin_amdgcn_mfma_f32_16x16x32_bf16(afr0, b, acc[0][tn], 0, 0, 0);
            acc[1][tn] = __builtin_amdgcn_mfma_f32_16x16x32_bf16(afr1, b, acc[1][tn], 0, 0, 0);
        }
    }

    int nlo = lane & 15, q = lane >> 4;
#pragma unroll
    for (int tA2 = 0; tA2 < 2; tA2++) {
#pragma unroll
        for (int r = 0; r < 4; r++) {
            int atom = a0 + tA2 * 16 + q * 4 + r;
            if (atom < N_ATOMS) {
#pragma unroll
                for (int tn = 0; tn < 4; tn++) {
                    int col = w * 64 + tn * 16 + nlo;
                    float vv = tssr2f(acc[tA2][tn][r] + bias[col]);
                    if (LAYER == 0) {
                        out[(size_t)atom * DINP1 + col] = vv;
                    } else {
                        out[(size_t)atom * 256 + col] = vv + skip[(size_t)atom * DINP1 + col];
                    }
                }
            }
        }
    }
}

// ------------------------------------------------------------------
extern "C" void kernel_launch(void* const* d_in, const int* in_sizes, int n_in,
                              void* d_out, int out_size, void* d_ws, size_t ws_size,
                              hipStream_t stream) {
    const int*   species     = (const int*)d_in[0];
    const int*   edge_src    = (const int*)d_in[1];
    const int*   edge_dst    = (const int*)d_in[2];
    const float* distances   = (const float*)d_in[3];
    const float* sw          = (const float*)d_in[4];
    const float* angles      = (const float*)d_in[5];
    const int*   angle_src   = (const int*)d_in[6];
    const int*   angle_dst   = (const int*)d_in[7];
    const int*   central     = (const int*)d_in[8];
    const float* dist_a      = (const float*)d_in[9];
    const float* sw_a        = (const float*)d_in[10];
    const float* table       = (const float*)d_in[11];
    const float* W_si0       = (const float*)d_in[12];
    const float* W_si1       = (const float*)d_in[13];
    const float* W_da0       = (const float*)d_in[14];
    const float* W_da1       = (const float*)d_in[15];
    const float* W_mix0      = (const float*)d_in[16];
    const float* b_mix0      = (const float*)d_in[17];
    const float* W_mix1      = (const float*)d_in[18];
    const float* b_mix1      = (const float*)d_in[19];
    float* out = (float*)d_out;

    char* p = (char*)d_ws;
    auto alloc = [&](size_t bytes) {
        char* r = p;
        p += (bytes + 255) & ~(size_t)255;
        return (void*)r;
    };
    float*  ei0  = (float*)alloc((size_t)N_ATOMS * DINP0 * 4);
    float*  ei1  = (float*)alloc((size_t)N_ATOMS * DINP1 * 4);
    float*  sd   = (float*)alloc((size_t)N_ATOMS * 32 * 4);
    unsigned short* dah = (unsigned short*)alloc((size_t)NEA * 8 * 2);
    float4* epay = (float4*)alloc((size_t)NE * 16);
    float4* tpay = (float4*)alloc((size_t)NT * 16);
    bf8*    Wf0  = (bf8*)alloc((size_t)(DINP0 / 32) * 16 * 64 * 16);
    bf8*    Wf1  = (bf8*)alloc((size_t)(DINP1 / 32) * 16 * 64 * 16);
    bf8*    WfS1 = (bf8*)alloc((size_t)8 * 6 * 64 * 16);
    int* eoff   = (int*)alloc((size_t)(N_ATOMS + 1) * 4);
    int* toff   = (int*)alloc((size_t)(N_ATOMS + 1) * 4);
    int* ebcnt  = (int*)alloc((size_t)NBUK * 4);
    int* tbcnt  = (int*)alloc((size_t)NBUK * 4);
    int* ebkoff = (int*)alloc((size_t)(NBUK + 1) * 4);
    int* tbkoff = (int*)alloc((size_t)(NBUK + 1) * 4);
    int* gce    = (int*)alloc((size_t)NBUK * 4);
    int* gct    = (int*)alloc((size_t)NBUK * 4);
    (void)ws_size;

    // bucket staging arrays alias ei1 (written only later by k_gemm<0>)
    float4* tbuk = (float4*)ei1;
    float4* ebuk = (float4*)((char*)ei1 + (size_t)NT * 16);

    hipMemsetAsync(ebcnt, 0, (size_t)NBUK * 4, stream);
    hipMemsetAsync(tbcnt, 0, (size_t)NBUK * 4, stream);

    int nfrag0 = (DINP0 / 32) * 16 * 64;
    int nfrag1 = (DINP1 / 32) * 16 * 64;
    int nfragS = 8 * 6 * 64;
    k_wprep<<<(nfrag0 + 255) / 256, 256, 0, stream>>>(W_mix0, Wf0, DIN0, 256, 16, nfrag0);
    k_wprep<<<(nfrag1 + 255) / 256, 256, 0, stream>>>(W_mix1, Wf1, DIN1, 256, 16, nfrag1);
    k_wprep<<<(nfragS + 255) / 256, 256, 0, stream>>>(W_si1, WfS1, 256, 96, 6, nfragS);

    k_bcount<<<EBLK + (NT + 4095) / 4096, 256, 0, stream>>>(edge_src, central, ebcnt, tbcnt);
    k_scanB<<<2, 512, 0, stream>>>(ebcnt, ebkoff, gce, eoff, tbcnt, tbkoff, gct, toff);

    k_binA<true><<<(NE + 4095) / 4096, 512, 0, stream>>>(
        distances, sw, nullptr, edge_dst, edge_src, gce, ebuk, NE);
    k_binA<false><<<(NT + 4095) / 4096, 512, 0, stream>>>(
        angles, nullptr, angle_src, angle_dst, central, gct, tbuk, NT);
    k_binB<<<NBUK, 256, 0, stream>>>(ebkoff, ebuk, epay, eoff);
    k_binB<<<NBUK, 256, 0, stream>>>(tbkoff, tbuk, tpay, toff);

    int gemm_grid = (N_ATOMS + 31) / 32;
    int seg_grid = (N_ATOMS + 3) / 4;

    // ---- layer 0 ----
    k_s0<<<(N_ATOMS * 120 + 255) / 256, 256, 0, stream>>>(species, table, W_si0, ei0, sd);
    k_da<<<(NEA + 255) / 256, 256, 0, stream>>>(dist_a, sw_a, W_da0, dah);
    k_mi<<<seg_grid, 256, 0, stream>>>(eoff, epay, sd, ei0 + 80, DINP0);
    k_ami<<<seg_grid, 256, 0, stream>>>(toff, tpay, dah, ei0 + 336, DINP0);
    k_gemm<0><<<gemm_grid, 256, 0, stream>>>(ei0, Wf0, b_mix0, nullptr, ei1);

    // ---- layer 1 ----
    k_s1<<<(N_ATOMS + 63) / 64, 256, 0, stream>>>(ei1, WfS1, ei1, sd);
    k_da<<<(NEA + 255) / 256, 256, 0, stream>>>(dist_a, sw_a, W_da1, dah);
    k_mi<<<seg_grid, 256, 0, stream>>>(eoff, epay, sd, ei1 + 320, DINP1);
    k_ami<<<seg_grid, 256, 0, stream>>>(toff, tpay, dah, ei1 + 576, DINP1);
    k_gemm<1><<<gemm_grid, 256, 0, stream>>>(ei1, Wf1, b_mix1, ei1, out);
}

// Round 11
// 483.195 us; speedup vs baseline: 1.6114x; 1.1861x over previous
//
#include <hip/hip_runtime.h>
#include <hip/hip_bf16.h>

typedef __hip_bfloat16 bf16;
typedef __bf16 bf8 __attribute__((ext_vector_type(8)));
typedef float  f4  __attribute__((ext_vector_type(4)));

#define N_ATOMS 25000
#define NE      800000
#define NEA     300000
#define NT      1600000
#define APB     64
#define NBUK    ((N_ATOMS + APB - 1) / APB)   // 391

#define DIN0  376
#define DIN1  616
#define DINP0 384
#define DINP1 640

#define EBLK ((NE + 4095) / 4096)   // 196

__device__ __forceinline__ float tssr2f(float x) {
    float ax = fabsf(x);
    return (ax <= 1.f) ? x : copysignf(2.f * __builtin_sqrtf(ax) - 1.f, x);
}

__device__ __forceinline__ unsigned short f2bf_rn(float v) {
    unsigned int b = __float_as_uint(v);
    b += 0x7FFF + ((b >> 16) & 1);
    return (unsigned short)(b >> 16);
}
__device__ __forceinline__ float bf2f(unsigned short u) {
    return __uint_as_float(((unsigned int)u) << 16);
}

// ------------------------------------------------------------------
// Bucket-granularity count
// ------------------------------------------------------------------
__global__ __launch_bounds__(256) void k_bcount(const int* __restrict__ esrc,
                                                const int* __restrict__ cat,
                                                int* __restrict__ ebcnt,
                                                int* __restrict__ tbcnt) {
    __shared__ int h[NBUK];
    int t = threadIdx.x;
    for (int b = t; b < NBUK; b += 256) h[b] = 0;
    __syncthreads();
    bool isE = blockIdx.x < EBLK;
    const int* key = isE ? esrc : cat;
    int n = isE ? NE : NT;
    int base = (isE ? blockIdx.x : (blockIdx.x - EBLK)) * 4096;
#pragma unroll
    for (int k = 0; k < 16; k++) {
        int idx = base + k * 256 + t;
        if (idx < n) atomicAdd(&h[key[idx] >> 6], 1);
    }
    __syncthreads();
    int* g = isE ? ebcnt : tbcnt;
    for (int b = t; b < NBUK; b += 256)
        if (h[b]) atomicAdd(&g[b], h[b]);
}

// ------------------------------------------------------------------
// Scan 391 bucket counts
// ------------------------------------------------------------------
__global__ __launch_bounds__(512) void k_scanB(const int* cnt0, int* off0, int* cur0,
                                               int* aoff0,
                                               const int* cnt1, int* off1, int* cur1,
                                               int* aoff1) {
    const int* cnt = blockIdx.x ? cnt1 : cnt0;
    int* off  = blockIdx.x ? off1 : off0;
    int* cur  = blockIdx.x ? cur1 : cur0;
    int* aoff = blockIdx.x ? aoff1 : aoff0;
    int nelem = blockIdx.x ? NT : NE;
    __shared__ int sh[512];
    int t = threadIdx.x;
    int v = (t < NBUK) ? cnt[t] : 0;
    sh[t] = v;
    __syncthreads();
    for (int d = 1; d < 512; d <<= 1) {
        int a = (t >= d) ? sh[t - d] : 0;
        __syncthreads();
        sh[t] += a;
        __syncthreads();
    }
    int excl = sh[t] - v;
    if (t <= NBUK) { off[t] = excl; if (t < NBUK) cur[t] = excl; }
    if (t == 0) aoff[N_ATOMS] = nelem;
}

// ------------------------------------------------------------------
// Phase A: bin payloads into coarse buckets
// ------------------------------------------------------------------
template <bool EDGE>
__global__ __launch_bounds__(512) void k_binA(const float* __restrict__ fA,
                                              const float* __restrict__ fB,
                                              const int* __restrict__ iB,
                                              const int* __restrict__ iC,
                                              const int* __restrict__ key,
                                              int* __restrict__ gcur,
                                              float4* __restrict__ buk, int n) {
    __shared__ int cnt[NBUK];
    __shared__ int rbase[NBUK];
    int t = threadIdx.x;
    for (int b = t; b < NBUK; b += 512) cnt[b] = 0;
    __syncthreads();
    int base = blockIdx.x * 4096;
    float4 pay[8];
    int bk[8], off[8];
#pragma unroll
    for (int k = 0; k < 8; k++) {
        int idx = base + k * 512 + t;
        bk[k] = -1;
        if (idx < n) {
            float4 p;
            p.x = fA[idx];
            p.y = EDGE ? fB[idx] : __int_as_float(iB[idx]);
            p.z = __int_as_float(iC[idx]);
            int ky = key[idx];
            p.w = __int_as_float(ky);
            pay[k] = p;
            bk[k] = ky >> 6;
            off[k] = atomicAdd(&cnt[bk[k]], 1);
        }
    }
    __syncthreads();
    for (int b = t; b < NBUK; b += 512)
        if (cnt[b]) rbase[b] = atomicAdd(&gcur[b], cnt[b]);
    __syncthreads();
#pragma unroll
    for (int k = 0; k < 8; k++)
        if (bk[k] >= 0) buk[rbase[bk[k]] + off[k]] = pay[k];
}

// ------------------------------------------------------------------
// Phase B: one workgroup per bucket
// ------------------------------------------------------------------
__global__ __launch_bounds__(256) void k_binB(const int* __restrict__ bkoff,
                                              const float4* __restrict__ buk,
                                              float4* __restrict__ fin,
                                              int* __restrict__ aoff) {
    int b = blockIdx.x;
    int lo = b * APB;
    int hi = min(lo + APB, N_ATOMS);
    __shared__ int cnt[APB];
    __shared__ int cur[APB];
    int t = threadIdx.x;
    if (t < APB) cnt[t] = 0;
    __syncthreads();
    int pbeg = bkoff[b], pend = bkoff[b + 1];
    for (int p = pbeg + t; p < pend; p += 256) {
        int a = __float_as_int(((const float*)(buk + p))[3]);
        atomicAdd(&cnt[a - lo], 1);
    }
    __syncthreads();
    if (t == 0) {
        int run = pbeg;
        for (int k = 0; k < hi - lo; k++) {
            cur[k] = run;
            aoff[lo + k] = run;
            run += cnt[k];
        }
    }
    __syncthreads();
    for (int p = pbeg + t; p < pend; p += 256) {
        float4 pay = buk[p];
        int a = __float_as_int(pay.w);
        int slot = atomicAdd(&cur[a - lo], 1);
        fin[slot] = pay;
    }
}

// ------------------------------------------------------------------
// W -> bf16 fragment layout (generalized)
// ------------------------------------------------------------------
__global__ void k_wprep(const float* __restrict__ W, bf8* __restrict__ Wf,
                        int K, int N, int ntiles, int nfrag) {
    int f = blockIdx.x * blockDim.x + threadIdx.x;
    if (f >= nfrag) return;
    int lane = f & 63;
    int ft = f >> 6;
    int tile = ft % ntiles;
    int chunk = ft / ntiles;
    int n = tile * 16 + (lane & 15);
    int kb = chunk * 32 + (lane >> 4) * 8;
    bf8 v;
#pragma unroll
    for (int j = 0; j < 8; j++) {
        int k = kb + j;
        v[j] = (__bf16)((k < K) ? W[k * N + n] : 0.f);
    }
    Wf[f] = v;
}

// ------------------------------------------------------------------
// layer 0
// ------------------------------------------------------------------
__global__ void k_s0(const int* __restrict__ sp, const float* __restrict__ table,
                     const float* __restrict__ W, float* __restrict__ ei0,
                     float* __restrict__ sd) {
    int idx = blockIdx.x * blockDim.x + threadIdx.x;
    if (idx >= N_ATOMS * 120) return;
    int i = idx / 120;
    int c = idx - i * 120;
    if (c >= 112) {
        ei0[(size_t)i * DINP0 + 376 + (c - 112)] = 0.f;
        return;
    }
    int s = sp[i];
    if (c < 16) {
        ei0[(size_t)i * DINP0 + c] = table[s * 16 + c];
    } else {
        int cc = c - 16;
        float acc = 0.f;
#pragma unroll
        for (int k = 0; k < 16; k++)
            acc += table[s * 16 + k] * W[k * 96 + cc];
        if (cc < 64) ei0[(size_t)i * DINP0 + 16 + cc] = acc;
        else         sd[i * 32 + cc - 64]             = acc;
    }
}

// ------------------------------------------------------------------
// layer 1 s: MFMA GEMM 25000x96
// ------------------------------------------------------------------
__global__ __launch_bounds__(256) void k_s1(const float* __restrict__ ei1,
                                            const bf8* __restrict__ Wf,
                                            float* __restrict__ ei1o,
                                            float* __restrict__ sd) {
    __shared__ __align__(16) __bf16 Asg[4][64][8];
    int t = threadIdx.x;
    int w = t >> 6, lane = t & 63;
    int a0 = blockIdx.x * 64;

    int satom = a0 + (t >> 2);
    int k8 = (t & 3) * 8;
    const float* arow = &ei1[(size_t)satom * DINP1 + k8];
    bool aok = satom < N_ATOMS;
    int dw = (t >> 2) >> 4;
    int dl = ((t >> 2) & 15) | ((t & 3) << 4);
    __bf16* adst = &Asg[dw][dl][0];

    f4 acc[6];
#pragma unroll
    for (int j = 0; j < 6; j++) {
        f4 z = {0.f, 0.f, 0.f, 0.f};
        acc[j] = z;
    }

    for (int ch = 0; ch < 8; ch++) {
        float4 v0 = make_float4(0.f, 0.f, 0.f, 0.f);
        float4 v1 = make_float4(0.f, 0.f, 0.f, 0.f);
        if (aok) {
            v0 = *(const float4*)(arow + ch * 32);
            v1 = *(const float4*)(arow + ch * 32 + 4);
        }
        __syncthreads();
        adst[0] = (__bf16)v0.x; adst[1] = (__bf16)v0.y;
        adst[2] = (__bf16)v0.z; adst[3] = (__bf16)v0.w;
        adst[4] = (__bf16)v1.x; adst[5] = (__bf16)v1.y;
        adst[6] = (__bf16)v1.z; adst[7] = (__bf16)v1.w;
        __syncthreads();
        bf8 afr = *(const bf8*)&Asg[w][lane][0];
        const bf8* wp = &Wf[(ch * 6) * 64 + lane];
#pragma unroll
        for (int tn = 0; tn < 6; tn++) {
            bf8 b = wp[tn * 64];
            acc[tn] = __builtin_amdgcn_mfma_f32_16x16x32_bf16(afr, b, acc[tn], 0, 0, 0);
        }
    }

    int nlo = lane & 15, q = lane >> 4;
#pragma unroll
    for (int r = 0; r < 4; r++) {
        int atom = a0 + w * 16 + q * 4 + r;
        if (atom < N_ATOMS) {
#pragma unroll
            for (int tn = 0; tn < 6; tn++) {
                int col = tn * 16 + nlo;
                float v = acc[tn][r];
                if (col < 64) ei1o[(size_t)atom * DINP1 + 256 + col] = v;
                else          sd[atom * 32 + col - 64] = v;
            }
        }
    }
    for (int z = t; z < 64 * 24; z += 256) {
        int za = a0 + z / 24;
        if (za < N_ATOMS) ei1o[(size_t)za * DINP1 + 616 + z % 24] = 0.f;
    }
}

// ------------------------------------------------------------------
// da -> bf16 (EA x 8)
// ------------------------------------------------------------------
__global__ void k_da(const float* __restrict__ dist, const float* __restrict__ sw,
                     const float* __restrict__ W, unsigned short* __restrict__ dah) {
    int e = blockIdx.x * blockDim.x + threadIdx.x;
    if (e >= NEA) return;
    float d = dist[e];
    float s = sw[e];
    float rb[8];
#pragma unroll
    for (int n = 0; n < 8; n++)
        rb[n] = 0.7559289460f * __sinf((n + 1) * 0.8975979010f * d) / d * s;
    unsigned short h[8];
#pragma unroll
    for (int c = 0; c < 8; c++) {
        float acc = 0.f;
#pragma unroll
        for (int n = 0; n < 8; n++) acc += rb[n] * W[n * 8 + c];
        h[c] = f2bf_rn(acc);
    }
    *(uint4*)&dah[e * 8] = *(uint4*)h;
}

// ------------------------------------------------------------------
// mi: one WAVE per atom; branchless full groups of 8, masked tail.
// ------------------------------------------------------------------
__global__ __launch_bounds__(256) void k_mi(const int* __restrict__ eoff,
                                            const float4* __restrict__ epay,
                                            const float* __restrict__ sd,
                                            float* __restrict__ mo, int stride) {
    int t = threadIdx.x;
    int w = t >> 6, l = t & 63;
    int i = blockIdx.x * 4 + w;
    if (i >= N_ATOMS) return;
    int beg = eoff[i], end = eoff[i + 1];
    int n = l >> 3, cb = (l & 7) * 4;
    float kn = (n + 1) * 0.6283185307f;
    float4 acc = make_float4(0.f, 0.f, 0.f, 0.f);
    int base = beg;
    for (; base + 8 <= end; base += 8) {
#pragma unroll
        for (int j = 0; j < 8; j++) {
            float4 ep = epay[base + j];
            float d = ep.x, s = ep.y;
            int di = __float_as_int(ep.z);
            float rb = 0.6324555320f * __sinf(kn * d) / d * s;
            float4 v = *(const float4*)&sd[di * 32 + cb];
            acc.x += rb * v.x; acc.y += rb * v.y;
            acc.z += rb * v.z; acc.w += rb * v.w;
        }
    }
    if (base < end) {
        int m = end - base;
#pragma unroll
        for (int j = 0; j < 8; j++) {
            int p = base + min(j, m - 1);
            float4 ep = epay[p];
            float d = ep.x, s = ep.y;
            int di = __float_as_int(ep.z);
            float mask = (j < m) ? 1.f : 0.f;
            float rb = mask * 0.6324555320f * __sinf(kn * d) / d * s;
            float4 v = *(const float4*)&sd[di * 32 + cb];
            acc.x += rb * v.x; acc.y += rb * v.y;
            acc.z += rb * v.z; acc.w += rb * v.w;
        }
    }
    *(float4*)&mo[(size_t)i * stride + n * 32 + cb] = acc;
}

// ------------------------------------------------------------------
// ami: one WAVE per atom, ALL 64 lanes: lane = (j<<3)|c, j = triplet-in-group,
// c = da column. Chebyshev recurrence replaces 5 cos with 1 cos + 4 fma.
// Cross-lane reduction over j (shfl_xor 8/16/32) at the end.
// ------------------------------------------------------------------
__global__ __launch_bounds__(256) void k_ami(const int* __restrict__ toff,
                                             const float4* __restrict__ tpay,
                                             const unsigned short* __restrict__ dah,
                                             float* __restrict__ ao, int stride) {
    int t = threadIdx.x;
    int w = t >> 6, l = t & 63;
    int i = blockIdx.x * 4 + w;
    if (i >= N_ATOMS) return;
    int beg = toff[i], end = toff[i + 1];
    int j = l >> 3, c = l & 7;
    float a0 = 0.f, a1 = 0.f, a2 = 0.f, a3 = 0.f, a4 = 0.f;
    int base = beg;
    for (; base + 8 <= end; base += 8) {
        float4 tp = tpay[base + j];
        int ea = __float_as_int(tp.y), eb = __float_as_int(tp.z);
        float dij = bf2f(dah[ea * 8 + c]) * bf2f(dah[eb * 8 + c]);
        float c1 = __cosf(tp.x);
        float c2 = __builtin_fmaf(2.f * c1, c1, -1.f);
        float c3 = __builtin_fmaf(2.f * c1, c2, -c1);
        float c4 = __builtin_fmaf(2.f * c1, c3, -c2);
        a0 += dij;
        a1 = __builtin_fmaf(c1, dij, a1);
        a2 = __builtin_fmaf(c2, dij, a2);
        a3 = __builtin_fmaf(c3, dij, a3);
        a4 = __builtin_fmaf(c4, dij, a4);
    }
    if (base < end) {
        int m = end - base;
        int p = base + min(j, m - 1);
        float4 tp = tpay[p];
        int ea = __float_as_int(tp.y), eb = __float_as_int(tp.z);
        float mask = (j < m) ? 1.f : 0.f;
        float dij = mask * bf2f(dah[ea * 8 + c]) * bf2f(dah[eb * 8 + c]);
        float c1 = __cosf(tp.x);
        float c2 = __builtin_fmaf(2.f * c1, c1, -1.f);
        float c3 = __builtin_fmaf(2.f * c1, c2, -c1);
        float c4 = __builtin_fmaf(2.f * c1, c3, -c2);
        a0 += dij;
        a1 = __builtin_fmaf(c1, dij, a1);
        a2 = __builtin_fmaf(c2, dij, a2);
        a3 = __builtin_fmaf(c3, dij, a3);
        a4 = __builtin_fmaf(c4, dij, a4);
    }
    // reduce over j (lanes l, l^8, l^16, l^32)
#pragma unroll
    for (int msk = 8; msk <= 32; msk <<= 1) {
        a0 += __shfl_xor(a0, msk, 64);
        a1 += __shfl_xor(a1, msk, 64);
        a2 += __shfl_xor(a2, msk, 64);
        a3 += __shfl_xor(a3, msk, 64);
        a4 += __shfl_xor(a4, msk, 64);
    }
    if (l < 8) {
        float* o = &ao[(size_t)i * stride + c];
        o[0]  = a0;
        o[8]  = a1;
        o[16] = a2;
        o[24] = a3;
        o[32] = a4;
    }
}

// ------------------------------------------------------------------
// MFMA GEMM: dxi = tssr2(ei @ W + b)
// ------------------------------------------------------------------
template <int LAYER>
__global__ __launch_bounds__(256) void k_gemm(const float* __restrict__ ei,
                                              const bf8* __restrict__ Wf,
                                              const float* __restrict__ bias,
                                              const float* __restrict__ skip,
                                              float* __restrict__ out) {
    constexpr int DINP = (LAYER == 0) ? DINP0 : DINP1;
    constexpr int NCH = DINP / 32;
    __shared__ __align__(16) __bf16 Asg[2][64][8];
    int t = threadIdx.x;
    int w = t >> 6, lane = t & 63;
    int a0 = blockIdx.x * 32;

    int f  = t * 4;
    int tA = f >> 9;
    int al = (f >> 3) & 63;
    int j0 = f & 7;
    int sm = al & 15, sq = al >> 4;
    int ga = a0 + tA * 16 + sm;
    const float* arow = &ei[(size_t)ga * DINP + sq * 8 + j0];
    __bf16* adst = &Asg[0][0][0] + f;
    bool aok = (ga < N_ATOMS);

    f4 acc[2][4];
#pragma unroll
    for (int i = 0; i < 2; i++)
#pragma unroll
        for (int j = 0; j < 4; j++) {
            f4 z = {0.f, 0.f, 0.f, 0.f};
            acc[i][j] = z;
        }

    for (int ch = 0; ch < NCH; ch++) {
        float4 v = make_float4(0.f, 0.f, 0.f, 0.f);
        if (aok) v = *(const float4*)(arow + ch * 32);
        __syncthreads();
        adst[0] = (__bf16)v.x; adst[1] = (__bf16)v.y;
        adst[2] = (__bf16)v.z; adst[3] = (__bf16)v.w;
        __syncthreads();
        bf8 afr0 = *(const bf8*)&Asg[0][lane][0];
        bf8 afr1 = *(const bf8*)&Asg[1][lane][0];
        const bf8* wp = &Wf[(ch * 16 + w * 4) * 64 + lane];
#pragma unroll
        for (int tn = 0; tn < 4; tn++) {
            bf8 b = wp[tn * 64];
            acc[0][tn] = __builtin_amdgcn_mfma_f32_16x16x32_bf16(afr0, b, acc[0][tn], 0, 0, 0);
            acc[1][tn] = __builtin_amdgcn_mfma_f32_16x16x32_bf16(afr1, b, acc[1][tn], 0, 0, 0);
        }
    }

    int nlo = lane & 15, q = lane >> 4;
#pragma unroll
    for (int tA2 = 0; tA2 < 2; tA2++) {
#pragma unroll
        for (int r = 0; r < 4; r++) {
            int atom = a0 + tA2 * 16 + q * 4 + r;
            if (atom < N_ATOMS) {
#pragma unroll
                for (int tn = 0; tn < 4; tn++) {
                    int col = w * 64 + tn * 16 + nlo;
                    float vv = tssr2f(acc[tA2][tn][r] + bias[col]);
                    if (LAYER == 0) {
                        out[(size_t)atom * DINP1 + col] = vv;
                    } else {
                        out[(size_t)atom * 256 + col] = vv + skip[(size_t)atom * DINP1 + col];
                    }
                }
            }
        }
    }
}

// ------------------------------------------------------------------
extern "C" void kernel_launch(void* const* d_in, const int* in_sizes, int n_in,
                              void* d_out, int out_size, void* d_ws, size_t ws_size,
                              hipStream_t stream) {
    const int*   species     = (const int*)d_in[0];
    const int*   edge_src    = (const int*)d_in[1];
    const int*   edge_dst    = (const int*)d_in[2];
    const float* distances   = (const float*)d_in[3];
    const float* sw          = (const float*)d_in[4];
    const float* angles      = (const float*)d_in[5];
    const int*   angle_src   = (const int*)d_in[6];
    const int*   angle_dst   = (const int*)d_in[7];
    const int*   central     = (const int*)d_in[8];
    const float* dist_a      = (const float*)d_in[9];
    const float* sw_a        = (const float*)d_in[10];
    const float* table       = (const float*)d_in[11];
    const float* W_si0       = (const float*)d_in[12];
    const float* W_si1       = (const float*)d_in[13];
    const float* W_da0       = (const float*)d_in[14];
    const float* W_da1       = (const float*)d_in[15];
    const float* W_mix0      = (const float*)d_in[16];
    const float* b_mix0      = (const float*)d_in[17];
    const float* W_mix1      = (const float*)d_in[18];
    const float* b_mix1      = (const float*)d_in[19];
    float* out = (float*)d_out;

    char* p = (char*)d_ws;
    auto alloc = [&](size_t bytes) {
        char* r = p;
        p += (bytes + 255) & ~(size_t)255;
        return (void*)r;
    };
    float*  ei0  = (float*)alloc((size_t)N_ATOMS * DINP0 * 4);
    float*  ei1  = (float*)alloc((size_t)N_ATOMS * DINP1 * 4);
    float*  sd   = (float*)alloc((size_t)N_ATOMS * 32 * 4);
    unsigned short* dah = (unsigned short*)alloc((size_t)NEA * 8 * 2);
    float4* epay = (float4*)alloc((size_t)NE * 16);
    float4* tpay = (float4*)alloc((size_t)NT * 16);
    bf8*    Wf0  = (bf8*)alloc((size_t)(DINP0 / 32) * 16 * 64 * 16);
    bf8*    Wf1  = (bf8*)alloc((size_t)(DINP1 / 32) * 16 * 64 * 16);
    bf8*    WfS1 = (bf8*)alloc((size_t)8 * 6 * 64 * 16);
    int* eoff   = (int*)alloc((size_t)(N_ATOMS + 1) * 4);
    int* toff   = (int*)alloc((size_t)(N_ATOMS + 1) * 4);
    int* ebcnt  = (int*)alloc((size_t)NBUK * 4);
    int* tbcnt  = (int*)alloc((size_t)NBUK * 4);
    int* ebkoff = (int*)alloc((size_t)(NBUK + 1) * 4);
    int* tbkoff = (int*)alloc((size_t)(NBUK + 1) * 4);
    int* gce    = (int*)alloc((size_t)NBUK * 4);
    int* gct    = (int*)alloc((size_t)NBUK * 4);
    (void)ws_size;

    // bucket staging arrays alias ei1 (written only later by k_gemm<0>)
    float4* tbuk = (float4*)ei1;
    float4* ebuk = (float4*)((char*)ei1 + (size_t)NT * 16);

    hipMemsetAsync(ebcnt, 0, (size_t)NBUK * 4, stream);
    hipMemsetAsync(tbcnt, 0, (size_t)NBUK * 4, stream);

    int nfrag0 = (DINP0 / 32) * 16 * 64;
    int nfrag1 = (DINP1 / 32) * 16 * 64;
    int nfragS = 8 * 6 * 64;
    k_wprep<<<(nfrag0 + 255) / 256, 256, 0, stream>>>(W_mix0, Wf0, DIN0, 256, 16, nfrag0);
    k_wprep<<<(nfrag1 + 255) / 256, 256, 0, stream>>>(W_mix1, Wf1, DIN1, 256, 16, nfrag1);
    k_wprep<<<(nfragS + 255) / 256, 256, 0, stream>>>(W_si1, WfS1, 256, 96, 6, nfragS);

    k_bcount<<<EBLK + (NT + 4095) / 4096, 256, 0, stream>>>(edge_src, central, ebcnt, tbcnt);
    k_scanB<<<2, 512, 0, stream>>>(ebcnt, ebkoff, gce, eoff, tbcnt, tbkoff, gct, toff);

    k_binA<true><<<(NE + 4095) / 4096, 512, 0, stream>>>(
        distances, sw, nullptr, edge_dst, edge_src, gce, ebuk, NE);
    k_binA<false><<<(NT + 4095) / 4096, 512, 0, stream>>>(
        angles, nullptr, angle_src, angle_dst, central, gct, tbuk, NT);
    k_binB<<<NBUK, 256, 0, stream>>>(ebkoff, ebuk, epay, eoff);
    k_binB<<<NBUK, 256, 0, stream>>>(tbkoff, tbuk, tpay, toff);

    int gemm_grid = (N_ATOMS + 31) / 32;
    int seg_grid = (N_ATOMS + 3) / 4;

    // ---- layer 0 ----
    k_s0<<<(N_ATOMS * 120 + 255) / 256, 256, 0, stream>>>(species, table, W_si0, ei0, sd);
    k_da<<<(NEA + 255) / 256, 256, 0, stream>>>(dist_a, sw_a, W_da0, dah);
    k_mi<<<seg_grid, 256, 0, stream>>>(eoff, epay, sd, ei0 + 80, DINP0);
    k_ami<<<seg_grid, 256, 0, stream>>>(toff, tpay, dah, ei0 + 336, DINP0);
    k_gemm<0><<<gemm_grid, 256, 0, stream>>>(ei0, Wf0, b_mix0, nullptr, ei1);

    // ---- layer 1 ----
    k_s1<<<(N_ATOMS + 63) / 64, 256, 0, stream>>>(ei1, WfS1, ei1, sd);
    k_da<<<(NEA + 255) / 256, 256, 0, stream>>>(dist_a, sw_a, W_da1, dah);
    k_mi<<<seg_grid, 256, 0, stream>>>(eoff, epay, sd, ei1 + 320, DINP1);
    k_ami<<<seg_grid, 256, 0, stream>>>(toff, tpay, dah, ei1 + 576, DINP1);
    k_gemm<1><<<gemm_grid, 256, 0, stream>>>(ei1, Wf1, b_mix1, ei1, out);
}